// Round 5
// baseline (526.720 us; speedup 1.0000x reference)
//
#include <hip/hip_runtime.h>
#include <hip/hip_bf16.h>

// B=1, H=4, T=1024, D=8192. fp32 in/out.
// O[h,t,d] = sum_{s<t} (ropeQ[h,t,:]·ropeQ[h,s,:]/sqrt(D)) * V[h,s,d]
// ws (86.2MB): Qr(bf16) 64MB [reused as Vt after s1] | Sbf(bf16) 8MB | part(bf16) 14.2MB
// s3: LDS-FREE register-fragment GEMM (Common-mistake #7: operands are L2/L3-resident;
// staging was pure overhead). Fragments load straight from global: A[r][kk+8*q4..+8].
// s1 keeps LDS staging (64MB working set, L3-scale) with dbuf prefetch.

typedef __bf16 bf16x8 __attribute__((ext_vector_type(8)));
typedef float  f32x4  __attribute__((ext_vector_type(4)));

#define HEAD_STRIDE (1024ull * 8192ull)   // elements per head, = 1<<23

__device__ inline void gl_lds16(const void* g, void* l) {
  __builtin_amdgcn_global_load_lds(
      (__attribute__((address_space(1))) void*)(g),
      (__attribute__((address_space(3))) void*)(l), 16, 0, 0);
}

// ---------------- RoPE (head-slicing reshape quirk), f32 -> bf16 ----------------
__global__ __launch_bounds__(256) void rope_kernel(const float* __restrict__ Q,
                                                   __bf16* __restrict__ Qr) {
  int gid = blockIdx.x * 256 + threadIdx.x;          // 4,194,304 threads x 8 elems
  size_t e8 = (size_t)gid * 8;
  int d0 = (int)(e8 & 8191);
  int t  = (int)((e8 >> 13) & 1023);
  int h  = (int)(e8 >> 23);

  f32x4 qa = *(const f32x4*)(Q + e8);
  f32x4 qb = *(const f32x4*)(Q + e8 + 4);
  int pt   = t & 1;
  int srct = ((h & 1) << 9) + (t >> 1);
  int sd   = (d0 >> 1) + (pt << 12);
  int hh   = h & ~1;
  size_t soff = ((size_t)srct << 13) + (size_t)sd;
  f32x4 a4 = *(const f32x4*)(Q + (size_t)(hh + 1) * HEAD_STRIDE + soff); // even d, sign -
  f32x4 b4 = *(const f32x4*)(Q + (size_t)hh       * HEAD_STRIDE + soff); // odd d,  sign +

  float qv[8];
#pragma unroll
  for (int i = 0; i < 4; ++i) { qv[i] = qa[i]; qv[4 + i] = qb[i]; }

  bf16x8 o;
  float tf = (float)t;
#pragma unroll
  for (int p = 0; p < 4; ++p) {
    float qd = (float)(d0 + 2 * p);
    float fr = exp2f(-qd * (1.0f / 512.0f)) * 0.15915494309189535f; // theta=2^16, /2pi
    float x = tf * fr;
    x -= floorf(x);
    float sn, cs;
    __sincosf(x * 6.283185307179586f, &sn, &cs);
    o[2 * p]     = (__bf16)(qv[2 * p]     * cs - a4[p] * sn);
    o[2 * p + 1] = (__bf16)(qv[2 * p + 1] * cs + b4[p] * sn);
  }
  *(bf16x8*)(Qr + e8) = o;
}

// ---------------- Stage 1: S[t,s] partials = scale * Qr[t,:]·Qr[s,:] ----------------
// grid = 4 heads * 36 lower-tri 128-tiles * splitK(4) = 576 blocks, K=2048 each.
// XCD-aware decode. split0 -> Sbf direct; splits 1-3 -> packed partials.
// LDS XOR-octet swizzled, double-buffered.
__global__ __launch_bounds__(256) void s1_qqt(const __bf16* __restrict__ Qr,
                                              __bf16* __restrict__ Sbf,
                                              __bf16* __restrict__ part) {
  __shared__ __align__(16) __bf16 As[2][128 * 64];
  __shared__ __align__(16) __bf16 Bs[2][128 * 64];
  int bid = blockIdx.x;
  int x = bid & 7;                                  // XCD
  int g = bid >> 3;                                 // 0..71
  int hi = (g >= 36) ? 1 : 0;
  int pair = g - 36 * hi;
  int c = x * 2 + hi;                               // (h,split) combo 0..15
  int h = c >> 2, split = c & 3;
  int ti = 0, p = pair;
  while (p > ti) { p -= ti + 1; ++ti; }
  int si = p;                                       // si <= ti

  const __bf16* Abase = Qr + (size_t)h * HEAD_STRIDE + ((size_t)(ti * 128) << 13) + split * 2048;
  const __bf16* Bbase = Qr + (size_t)h * HEAD_STRIDE + ((size_t)(si * 128) << 13) + split * 2048;

  int tid = threadIdx.x, lane = tid & 63, wave = tid >> 6;
  int wm = (wave & 1) << 6, wn = (wave >> 1) << 6;
  int l16 = lane & 15, q4 = lane >> 4;
  int srow = lane >> 3;                             // 0..7
  int scol = ((lane & 7) ^ srow) * 8;               // swizzled source octet

  auto stage = [&](int b, int kk) {
#pragma unroll
    for (int j = 0; j < 4; ++j) {
      int cc = wave * 4 + j;
      int row = cc * 8 + srow;
      gl_lds16(Abase + (size_t)row * 8192 + kk + scol, &As[b][cc * 512]);
      gl_lds16(Bbase + (size_t)row * 8192 + kk + scol, &Bs[b][cc * 512]);
    }
  };

  f32x4 acc[4][4] = {};

  stage(0, 0);
  __syncthreads();

  int cur = 0;
  for (int kk = 0; kk < 2048; kk += 64) {
    if (kk + 64 < 2048) stage(cur ^ 1, kk + 64);    // prefetch next tile (issued before compute)
#pragma unroll
    for (int ks = 0; ks < 64; ks += 32) {
      bf16x8 af[4], bfr[4];
#pragma unroll
      for (int i = 0; i < 4; ++i) {
        int r = wm + i * 16 + l16;
        af[i] = *(const bf16x8*)&As[cur][r * 64 + (((q4 + (ks >> 3)) ^ (r & 7)) << 3)];
      }
#pragma unroll
      for (int i = 0; i < 4; ++i) {
        int r = wn + i * 16 + l16;
        bfr[i] = *(const bf16x8*)&Bs[cur][r * 64 + (((q4 + (ks >> 3)) ^ (r & 7)) << 3)];
      }
#pragma unroll
      for (int i = 0; i < 4; ++i)
#pragma unroll
        for (int j = 0; j < 4; ++j)
          acc[i][j] = __builtin_amdgcn_mfma_f32_16x16x32_bf16(af[i], bfr[j], acc[i][j], 0, 0, 0);
    }
    __syncthreads();                                // prefetch landed; all waves synced
    cur ^= 1;
  }

  const float scale = 0.011048543456039806f;        // 1/sqrt(8192)
  if (split == 0) {
    // direct bf16 tile write into row-major Sbf (mask applied later by reduce)
    __bf16* Sh = Sbf + ((size_t)h << 20);
    int t_base = ti * 128 + wm, s_base = si * 128 + wn;
#pragma unroll
    for (int i = 0; i < 4; ++i)
#pragma unroll
      for (int j = 0; j < 4; ++j) {
        int col = s_base + j * 16 + l16;            // s
#pragma unroll
        for (int r = 0; r < 4; ++r) {
          int row = t_base + i * 16 + q4 * 4 + r;   // t
          Sh[((size_t)row << 10) + col] = (__bf16)(acc[i][j][r] * scale);
        }
      }
  } else {
    // packed partial tile [tile][split-1][128][128]
    __bf16* P = part + (((size_t)(h * 36 + pair) * 3 + (split - 1)) << 14);
#pragma unroll
    for (int i = 0; i < 4; ++i)
#pragma unroll
      for (int j = 0; j < 4; ++j) {
        int lcol = wn + j * 16 + l16;
#pragma unroll
        for (int r = 0; r < 4; ++r) {
          int lrow = wm + i * 16 + q4 * 4 + r;
          P[lrow * 128 + lcol] = (__bf16)(acc[i][j][r] * scale);
        }
      }
  }
}

// ---------------- reduce: Sbf += partials, strict-causal mask ----------------
// 144 lower-tri tiles * 16384 elems / 8 per thread = 294912 threads = 1152 blocks
__global__ __launch_bounds__(256) void reduce_kernel(const __bf16* __restrict__ part,
                                                     __bf16* __restrict__ Sbf) {
  int gid = blockIdx.x * 256 + threadIdx.x;
  int tile = gid >> 11;                             // 0..143 = h*36+pair
  int e = (gid & 2047) << 3;
  int row = e >> 7, col = e & 127;
  int h = tile / 36, pair = tile % 36;
  int ti = 0, p = pair;
  while (p > ti) { p -= ti + 1; ++ti; }
  int si = p;

  size_t soff = ((size_t)h << 20) + ((size_t)(ti * 128 + row) << 10) + si * 128 + col;
  bf16x8 s0 = *(const bf16x8*)(Sbf + soff);
  const __bf16* P = part + ((size_t)tile * 3 << 14) + row * 128 + col;
  bf16x8 p0 = *(const bf16x8*)(P);
  bf16x8 p1 = *(const bf16x8*)(P + 16384);
  bf16x8 p2 = *(const bf16x8*)(P + 32768);
  bool diag = (ti == si);
  bf16x8 o;
#pragma unroll
  for (int j = 0; j < 8; ++j) {
    float v = (float)s0[j] + (float)p0[j] + (float)p1[j] + (float)p2[j];
    if (diag && (col + j >= row)) v = 0.0f;         // strict causal on diagonal tiles
    o[j] = (__bf16)v;
  }
  *(bf16x8*)(Sbf + soff) = o;
}

// ---------------- V transpose+convert: Vt[h][d][s] = bf16(V[h][s][d]) ----------------
// grid = 4 h * 16 s-tiles * 128 d-tiles = 8192 blocks (64x64 tiles)
__global__ __launch_bounds__(256) void transp_kernel(const float* __restrict__ V,
                                                     __bf16* __restrict__ Vt) {
  __shared__ __bf16 L[64 * 72];                     // [d][s], pad 72
  int bid = blockIdx.x;
  int dtile = bid & 127;
  int st = (bid >> 7) & 15;
  int h = bid >> 11;
  int s0 = st << 6, d0 = dtile << 6;
  const float* Vh = V + (size_t)h * HEAD_STRIDE;
  __bf16* Vth = Vt + (size_t)h * HEAD_STRIDE;
  int tid = threadIdx.x;
  int r = tid >> 2;                                 // s-row 0..63
  int c = (tid & 3) << 4;                           // d-col base (16 cols)
#pragma unroll
  for (int j = 0; j < 4; ++j) {
    f32x4 v = *(const f32x4*)(Vh + (size_t)(s0 + r) * 8192 + d0 + c + 4 * j);
#pragma unroll
    for (int e = 0; e < 4; ++e) L[(c + 4 * j + e) * 72 + r] = (__bf16)v[e];
  }
  __syncthreads();
  int row = tid >> 3;                               // d-row 0..31
  int col8 = (tid & 7) << 3;
#pragma unroll
  for (int half = 0; half < 2; ++half) {
    int dr = row + half * 32;
    bf16x8 v = *(const bf16x8*)&L[dr * 72 + col8];
    *(bf16x8*)(Vth + (size_t)(d0 + dr) * 1024 + s0 + col8) = v;
  }
}

// ---------------- Stage 3: O[t,d] = sum_s S[t,s] * Vt[d,s] ----------------
// grid = 4 heads * 8 t-tiles * 64 d-tiles = 2048 blocks, long-K dispatched first.
// LDS-FREE: both operands are K-contiguous row-major and L2/L3-resident; MFMA
// fragments load directly from global (A[r][kk+8*q4..+8]), compiler register-
// pipelines across K. No barriers, no staging.
__global__ __launch_bounds__(256) void s3_sv(const __bf16* __restrict__ Sbf,
                                             const __bf16* __restrict__ Vt,
                                             float* __restrict__ out) {
  int bid = blockIdx.x;
  int dt = bid & 63; bid >>= 6;
  int tt = 7 - (bid & 7);                           // long-K blocks dispatched first
  int h = bid >> 3;

  int Kmax = tt * 128 + 128;

  int tid = threadIdx.x, lane = tid & 63, wave = tid >> 6;
  int wm = (wave & 1) << 6, wn = (wave >> 1) << 6;
  int l16 = lane & 15, q4 = lane >> 4;

  // per-fragment row base pointers (K-contiguous), offset by this lane's octet (8*q4)
  const __bf16* Ap[4];
  const __bf16* Bp[4];
  const __bf16* Abase = Sbf + ((size_t)h << 20) + ((size_t)(tt * 128) << 10) + q4 * 8;
  const __bf16* Bbase = Vt + (size_t)h * HEAD_STRIDE + ((size_t)(dt * 128) << 10) + q4 * 8;
#pragma unroll
  for (int i = 0; i < 4; ++i) {
    Ap[i] = Abase + (size_t)(wm + i * 16 + l16) * 1024;
    Bp[i] = Bbase + (size_t)(wn + i * 16 + l16) * 1024;
  }

  f32x4 acc[4][4] = {};

  for (int kk = 0; kk < Kmax; kk += 32) {
    bf16x8 af[4], bfr[4];
#pragma unroll
    for (int i = 0; i < 4; ++i) af[i]  = *(const bf16x8*)(Ap[i] + kk);
#pragma unroll
    for (int i = 0; i < 4; ++i) bfr[i] = *(const bf16x8*)(Bp[i] + kk);
#pragma unroll
    for (int i = 0; i < 4; ++i)
#pragma unroll
      for (int j = 0; j < 4; ++j)
        acc[i][j] = __builtin_amdgcn_mfma_f32_16x16x32_bf16(af[i], bfr[j], acc[i][j], 0, 0, 0);
  }

  int t_base = tt * 128 + wm, d_base = dt * 128 + wn;
  float* obase = out + (size_t)h * HEAD_STRIDE;
#pragma unroll
  for (int i = 0; i < 4; ++i)
#pragma unroll
    for (int j = 0; j < 4; ++j) {
      int col = d_base + j * 16 + l16;              // d
#pragma unroll
      for (int r = 0; r < 4; ++r) {
        int row = t_base + i * 16 + q4 * 4 + r;     // t
        obase[((size_t)row << 13) + col] = acc[i][j][r];
      }
    }
}

extern "C" void kernel_launch(void* const* d_in, const int* in_sizes, int n_in,
                              void* d_out, int out_size, void* d_ws, size_t ws_size,
                              hipStream_t stream) {
  const float* query = (const float*)d_in[0];
  const float* value = (const float*)d_in[1];
  float* out = (float*)d_out;

  char* ws = (char*)d_ws;
  __bf16* Qr   = (__bf16*)ws;                       // 64 MB; dead after s1 -> reused as Vt
  __bf16* Vt   = (__bf16*)ws;                       // aliases Qr (stream-ordered safe)
  __bf16* Sbf  = (__bf16*)(ws + 67108864);          //  8 MB
  __bf16* part = (__bf16*)(ws + 75497472);          // 14.2 MB (total 86.2 MB)

  hipMemsetAsync(Sbf, 0, 8388608, stream);
  rope_kernel<<<16384, 256, 0, stream>>>(query, Qr);
  s1_qqt<<<576, 256, 0, stream>>>(Qr, Sbf, part);
  reduce_kernel<<<1152, 256, 0, stream>>>(part, Sbf);
  transp_kernel<<<8192, 256, 0, stream>>>(value, Vt);  // overwrites Qr region (dead)
  s3_sv<<<2048, 256, 0, stream>>>(Sbf, Vt, out);
}

// Round 7
// 437.427 us; speedup vs baseline: 1.2041x; 1.2041x over previous
//
#include <hip/hip_runtime.h>
#include <hip/hip_bf16.h>

// B=1, H=4, T=1024, D=8192. fp32 in/out.
// O[h,t,d] = sum_{s<t} (ropeQ[h,t,:]·ropeQ[h,s,:]/sqrt(D)) * V[h,s,d]
// ws (86.2MB HARD CAP - 88MB workspace): Qr 64MB [reused as Vt] | Sbf 8MB | part 14.2MB
// R7 = recovery round from validated parts: s1 = R1's single-buffer 32KB splitK=4
// (all 576 blocks co-resident, no tail); s3 = R3's dbuf 2-phase (81us measured).
// memset dropped (split0 WRITES all lower-tri tiles; nothing s3 reads is uninit).

typedef __bf16 bf16x8 __attribute__((ext_vector_type(8)));
typedef float  f32x4  __attribute__((ext_vector_type(4)));

#define HEAD_STRIDE (1024ull * 8192ull)   // elements per head, = 1<<23

__device__ inline void gl_lds16(const void* g, void* l) {
  __builtin_amdgcn_global_load_lds(
      (__attribute__((address_space(1))) void*)(g),
      (__attribute__((address_space(3))) void*)(l), 16, 0, 0);
}

// ---------------- RoPE (head-slicing reshape quirk), f32 -> bf16 ----------------
__global__ __launch_bounds__(256) void rope_kernel(const float* __restrict__ Q,
                                                   __bf16* __restrict__ Qr) {
  int gid = blockIdx.x * 256 + threadIdx.x;          // 4,194,304 threads x 8 elems
  size_t e8 = (size_t)gid * 8;
  int d0 = (int)(e8 & 8191);
  int t  = (int)((e8 >> 13) & 1023);
  int h  = (int)(e8 >> 23);

  f32x4 qa = *(const f32x4*)(Q + e8);
  f32x4 qb = *(const f32x4*)(Q + e8 + 4);
  int pt   = t & 1;
  int srct = ((h & 1) << 9) + (t >> 1);
  int sd   = (d0 >> 1) + (pt << 12);
  int hh   = h & ~1;
  size_t soff = ((size_t)srct << 13) + (size_t)sd;
  f32x4 a4 = *(const f32x4*)(Q + (size_t)(hh + 1) * HEAD_STRIDE + soff); // even d, sign -
  f32x4 b4 = *(const f32x4*)(Q + (size_t)hh       * HEAD_STRIDE + soff); // odd d,  sign +

  float qv[8];
#pragma unroll
  for (int i = 0; i < 4; ++i) { qv[i] = qa[i]; qv[4 + i] = qb[i]; }

  bf16x8 o;
  float tf = (float)t;
#pragma unroll
  for (int p = 0; p < 4; ++p) {
    float qd = (float)(d0 + 2 * p);
    float fr = exp2f(-qd * (1.0f / 512.0f)) * 0.15915494309189535f; // theta=2^16, /2pi
    float x = tf * fr;
    x -= floorf(x);
    float sn, cs;
    __sincosf(x * 6.283185307179586f, &sn, &cs);
    o[2 * p]     = (__bf16)(qv[2 * p]     * cs - a4[p] * sn);
    o[2 * p + 1] = (__bf16)(qv[2 * p + 1] * cs + b4[p] * sn);
  }
  *(bf16x8*)(Qr + e8) = o;
}

// ---------------- Stage 1: S[t,s] partials = scale * Qr[t,:]·Qr[s,:] ----------------
// grid = 4 heads * 36 lower-tri 128-tiles * splitK(4) = 576 blocks, K=2048 each.
// XCD decode: each XCD owns 2 (h,split) combos x all 36 pairs. Single-buffer 32KB LDS
// -> up to 5 blk/CU capacity; 2.25 blk/CU actual, all co-resident (no tail rounds).
// split0 -> Sbf direct; splits 1-3 -> packed partials. LDS XOR-octet swizzled.
__global__ __launch_bounds__(256) void s1_qqt(const __bf16* __restrict__ Qr,
                                              __bf16* __restrict__ Sbf,
                                              __bf16* __restrict__ part) {
  __shared__ __align__(16) __bf16 As[128 * 64];
  __shared__ __align__(16) __bf16 Bs[128 * 64];
  int bid = blockIdx.x;
  int x = bid & 7;                                  // XCD
  int g = bid >> 3;                                 // 0..71
  int hi = (g >= 36) ? 1 : 0;
  int pair = g - 36 * hi;
  int c = x * 2 + hi;                               // (h,split) combo 0..15
  int h = c >> 2, split = c & 3;
  int ti = 0, p = pair;
  while (p > ti) { p -= ti + 1; ++ti; }
  int si = p;                                       // si <= ti

  const __bf16* Abase = Qr + (size_t)h * HEAD_STRIDE + ((size_t)(ti * 128) << 13) + split * 2048;
  const __bf16* Bbase = Qr + (size_t)h * HEAD_STRIDE + ((size_t)(si * 128) << 13) + split * 2048;

  int tid = threadIdx.x, lane = tid & 63, wave = tid >> 6;
  int wm = (wave & 1) << 6, wn = (wave >> 1) << 6;
  int l16 = lane & 15, q4 = lane >> 4;
  int srow = lane >> 3;                             // 0..7
  int scol = ((lane & 7) ^ srow) * 8;               // swizzled source octet

  f32x4 acc[4][4] = {};

  for (int kk = 0; kk < 2048; kk += 64) {
#pragma unroll
    for (int j = 0; j < 4; ++j) {
      int cc = wave * 4 + j;
      int row = cc * 8 + srow;
      gl_lds16(Abase + (size_t)row * 8192 + kk + scol, &As[cc * 512]);
      gl_lds16(Bbase + (size_t)row * 8192 + kk + scol, &Bs[cc * 512]);
    }
    __syncthreads();
#pragma unroll
    for (int ks = 0; ks < 64; ks += 32) {
      bf16x8 af[4], bfr[4];
#pragma unroll
      for (int i = 0; i < 4; ++i) {
        int r = wm + i * 16 + l16;
        af[i] = *(const bf16x8*)&As[r * 64 + (((q4 + (ks >> 3)) ^ (r & 7)) << 3)];
      }
#pragma unroll
      for (int i = 0; i < 4; ++i) {
        int r = wn + i * 16 + l16;
        bfr[i] = *(const bf16x8*)&Bs[r * 64 + (((q4 + (ks >> 3)) ^ (r & 7)) << 3)];
      }
#pragma unroll
      for (int i = 0; i < 4; ++i)
#pragma unroll
        for (int j = 0; j < 4; ++j)
          acc[i][j] = __builtin_amdgcn_mfma_f32_16x16x32_bf16(af[i], bfr[j], acc[i][j], 0, 0, 0);
    }
    __syncthreads();
  }

  const float scale = 0.011048543456039806f;        // 1/sqrt(8192)
  if (split == 0) {
    // direct bf16 tile write into row-major Sbf (mask applied later by reduce)
    __bf16* Sh = Sbf + ((size_t)h << 20);
    int t_base = ti * 128 + wm, s_base = si * 128 + wn;
#pragma unroll
    for (int i = 0; i < 4; ++i)
#pragma unroll
      for (int j = 0; j < 4; ++j) {
        int col = s_base + j * 16 + l16;            // s
#pragma unroll
        for (int r = 0; r < 4; ++r) {
          int row = t_base + i * 16 + q4 * 4 + r;   // t
          Sh[((size_t)row << 10) + col] = (__bf16)(acc[i][j][r] * scale);
        }
      }
  } else {
    // packed partial tile [tile][split-1][128][128]
    __bf16* P = part + (((size_t)(h * 36 + pair) * 3 + (split - 1)) << 14);
#pragma unroll
    for (int i = 0; i < 4; ++i)
#pragma unroll
      for (int j = 0; j < 4; ++j) {
        int lcol = wn + j * 16 + l16;
#pragma unroll
        for (int r = 0; r < 4; ++r) {
          int lrow = wm + i * 16 + q4 * 4 + r;
          P[lrow * 128 + lcol] = (__bf16)(acc[i][j][r] * scale);
        }
      }
  }
}

// ---------------- reduce: Sbf += 3 partials, strict-causal mask ----------------
// 144 lower-tri tiles * 16384 elems / 8 per thread = 294912 threads = 1152 blocks
__global__ __launch_bounds__(256) void reduce_kernel(const __bf16* __restrict__ part,
                                                     __bf16* __restrict__ Sbf) {
  int gid = blockIdx.x * 256 + threadIdx.x;
  int tile = gid >> 11;                             // 0..143 = h*36+pair
  int e = (gid & 2047) << 3;
  int row = e >> 7, col = e & 127;
  int h = tile / 36, pair = tile % 36;
  int ti = 0, p = pair;
  while (p > ti) { p -= ti + 1; ++ti; }
  int si = p;

  size_t soff = ((size_t)h << 20) + ((size_t)(ti * 128 + row) << 10) + si * 128 + col;
  bf16x8 s0 = *(const bf16x8*)(Sbf + soff);
  const __bf16* P = part + ((size_t)tile * 3 << 14) + row * 128 + col;
  bf16x8 p0 = *(const bf16x8*)(P);
  bf16x8 p1 = *(const bf16x8*)(P + 16384);
  bf16x8 p2 = *(const bf16x8*)(P + 32768);
  bool diag = (ti == si);
  bf16x8 o;
#pragma unroll
  for (int j = 0; j < 8; ++j) {
    float v = (float)s0[j] + (float)p0[j] + (float)p1[j] + (float)p2[j];
    if (diag && (col + j >= row)) v = 0.0f;         // strict causal on diagonal tiles
    o[j] = (__bf16)v;
  }
  *(bf16x8*)(Sbf + soff) = o;
}

// ---------------- V transpose+convert: Vt[h][d][s] = bf16(V[h][s][d]) ----------------
// grid = 4 h * 16 s-tiles * 128 d-tiles = 8192 blocks (64x64 tiles)
__global__ __launch_bounds__(256) void transp_kernel(const float* __restrict__ V,
                                                     __bf16* __restrict__ Vt) {
  __shared__ __bf16 L[64 * 72];                     // [d][s], pad 72
  int bid = blockIdx.x;
  int dtile = bid & 127;
  int st = (bid >> 7) & 15;
  int h = bid >> 11;
  int s0 = st << 6, d0 = dtile << 6;
  const float* Vh = V + (size_t)h * HEAD_STRIDE;
  __bf16* Vth = Vt + (size_t)h * HEAD_STRIDE;
  int tid = threadIdx.x;
  int r = tid >> 2;                                 // s-row 0..63
  int c = (tid & 3) << 4;                           // d-col base (16 cols)
#pragma unroll
  for (int j = 0; j < 4; ++j) {
    f32x4 v = *(const f32x4*)(Vh + (size_t)(s0 + r) * 8192 + d0 + c + 4 * j);
#pragma unroll
    for (int e = 0; e < 4; ++e) L[(c + 4 * j + e) * 72 + r] = (__bf16)v[e];
  }
  __syncthreads();
  int row = tid >> 3;                               // d-row 0..31
  int col8 = (tid & 7) << 3;
#pragma unroll
  for (int half = 0; half < 2; ++half) {
    int dr = row + half * 32;
    bf16x8 v = *(const bf16x8*)&L[dr * 72 + col8];
    *(bf16x8*)(Vth + (size_t)(d0 + dr) * 1024 + s0 + col8) = v;
  }
}

// ---------------- Stage 3: O[t,d] = sum_s S[t,s] * Vt[d,s], K truncated by causality ----------------
// grid = 4 heads * 8 t-tiles * 64 d-tiles = 2048 blocks. Double-buffered 2-phase (R3-proven).
__global__ __launch_bounds__(256) void s3_sv(const __bf16* __restrict__ Sbf,
                                             const __bf16* __restrict__ Vt,
                                             float* __restrict__ out) {
  __shared__ __align__(16) __bf16 As[2][128 * 64];
  __shared__ __align__(16) __bf16 Bs[2][128 * 64];
  int bid = blockIdx.x;
  int dt = bid & 63; bid >>= 6;
  int tt = 7 - (bid & 7);                           // long-K blocks dispatched first
  int h = bid >> 3;

  const __bf16* Abase = Sbf + ((size_t)h << 20) + ((size_t)(tt * 128) << 10);
  const __bf16* Bbase = Vt + (size_t)h * HEAD_STRIDE + ((size_t)(dt * 128) << 10);
  int Kmax = tt * 128 + 128;

  int tid = threadIdx.x, lane = tid & 63, wave = tid >> 6;
  int wm = (wave & 1) << 6, wn = (wave >> 1) << 6;
  int l16 = lane & 15, q4 = lane >> 4;
  int srow = lane >> 3;
  int scol = ((lane & 7) ^ srow) * 8;               // swizzled source octet

  auto stage = [&](int b, int kk) {
#pragma unroll
    for (int j = 0; j < 4; ++j) {
      int cc = wave * 4 + j;
      int row = cc * 8 + srow;
      gl_lds16(Abase + (size_t)row * 1024 + kk + scol, &As[b][cc * 512]);
      gl_lds16(Bbase + (size_t)row * 1024 + kk + scol, &Bs[b][cc * 512]);
    }
  };

  f32x4 acc[4][4] = {};

  stage(0, 0);
  __syncthreads();

  int cur = 0;
  for (int kk = 0; kk < Kmax; kk += 64) {
    if (kk + 64 < Kmax) stage(cur ^ 1, kk + 64);    // prefetch next tile (issued before compute)
#pragma unroll
    for (int ks = 0; ks < 64; ks += 32) {
      bf16x8 af[4], bfr[4];
#pragma unroll
      for (int i = 0; i < 4; ++i) {
        int r = wm + i * 16 + l16;
        af[i] = *(const bf16x8*)&As[cur][r * 64 + (((q4 + (ks >> 3)) ^ (r & 7)) << 3)];
      }
#pragma unroll
      for (int i = 0; i < 4; ++i) {
        int r = wn + i * 16 + l16;
        bfr[i] = *(const bf16x8*)&Bs[cur][r * 64 + (((q4 + (ks >> 3)) ^ (r & 7)) << 3)];
      }
#pragma unroll
      for (int i = 0; i < 4; ++i)
#pragma unroll
        for (int j = 0; j < 4; ++j)
          acc[i][j] = __builtin_amdgcn_mfma_f32_16x16x32_bf16(af[i], bfr[j], acc[i][j], 0, 0, 0);
    }
    __syncthreads();
    cur ^= 1;
  }

  int t_base = tt * 128 + wm, d_base = dt * 128 + wn;
  float* obase = out + (size_t)h * HEAD_STRIDE;
#pragma unroll
  for (int i = 0; i < 4; ++i)
#pragma unroll
    for (int j = 0; j < 4; ++j) {
      int col = d_base + j * 16 + l16;              // d
#pragma unroll
      for (int r = 0; r < 4; ++r) {
        int row = t_base + i * 16 + q4 * 4 + r;     // t
        obase[((size_t)row << 13) + col] = acc[i][j][r];
      }
    }
}

extern "C" void kernel_launch(void* const* d_in, const int* in_sizes, int n_in,
                              void* d_out, int out_size, void* d_ws, size_t ws_size,
                              hipStream_t stream) {
  const float* query = (const float*)d_in[0];
  const float* value = (const float*)d_in[1];
  float* out = (float*)d_out;

  char* ws = (char*)d_ws;
  __bf16* Qr   = (__bf16*)ws;                       // 64 MB; dead after s1 -> reused as Vt
  __bf16* Vt   = (__bf16*)ws;                       // aliases Qr (stream-ordered safe)
  __bf16* Sbf  = (__bf16*)(ws + 67108864);          //  8 MB
  __bf16* part = (__bf16*)(ws + 75497472);          // 14.2 MB (total 86.2 MB <= 88 MB cap)

  rope_kernel<<<16384, 256, 0, stream>>>(query, Qr);
  s1_qqt<<<576, 256, 0, stream>>>(Qr, Sbf, part);
  reduce_kernel<<<1152, 256, 0, stream>>>(part, Sbf);
  transp_kernel<<<8192, 256, 0, stream>>>(value, Vt);  // overwrites Qr region (dead)
  s3_sv<<<2048, 256, 0, stream>>>(Sbf, Vt, out);
}